// Round 2
// baseline (393.235 us; speedup 1.0000x reference)
//
#include <hip/hip_runtime.h>

// NodeNetwork fused kernel (f32, VALU): 64 nodes/block, 512 threads (8 waves).
// Wave w computes output j-slice w for all 64 nodes -> weight loads wave-uniform (s_load).
// 3 blocks/CU (52KB LDS) x 8 waves = 24 waves/CU for latency hiding.
constexpr int NB = 64;
constexpr int THREADS = 512;
constexpr int X1S = 132;   // x1 LDS row stride (128 cols, padded; stride%32==4 -> b128 slot=lane%8, conflict-free)
constexpr int H1S = 100;   // h1 LDS row stride (96 cols), aliases x1 region
constexpr int X2S = 68;    // x2/h2 LDS row stride (64 cols)

typedef float vf4 __attribute__((ext_vector_type(4)));

__device__ __forceinline__ float fast_tanh(float x) {
    // tanh(x) = 1 - 2/(exp(2x)+1); v_exp + v_rcp, rel err ~1e-6, saturates correctly.
    float e = __expf(2.0f * x);
    return 1.0f - 2.0f * __builtin_amdgcn_rcpf(e + 1.0f);
}

__global__ __launch_bounds__(THREADS, 6) void node_net_kernel(
    const float* __restrict__ feat, const float* __restrict__ hid,
    const float* __restrict__ mail,
    const float* __restrict__ w1a, const float* __restrict__ b1a,
    const float* __restrict__ w1b, const float* __restrict__ b1b,
    const float* __restrict__ w2a, const float* __restrict__ b2a,
    const float* __restrict__ w2b, const float* __restrict__ b2b,
    float* __restrict__ out)
{
    __shared__ float ldsA[NB * X1S];   // x1, later h1
    __shared__ float ldsB[NB * X2S];   // x2, later h2
    __shared__ float ldsS[NB * 8];     // per-sub partial sumsq

    const int t  = threadIdx.x;
    const int n0 = blockIdx.x * NB;

    // ---------- Phase 1: stage x1 = [feat|hid], mailbox-sum -> x2 (all nontemporal) ----------
    #pragma unroll
    for (int i = 0; i < 2; ++i) {
        int task = i * THREADS + t;            // 0..1023 = 64 nodes x 16 f4-cols
        int n = task >> 4, c4 = task & 15;
        vf4 f = __builtin_nontemporal_load(reinterpret_cast<const vf4*>(feat) + (size_t)(n0 + n) * 16 + c4);
        vf4 h = __builtin_nontemporal_load(reinterpret_cast<const vf4*>(hid ) + (size_t)(n0 + n) * 16 + c4);
        const vf4* ms = reinterpret_cast<const vf4*>(mail) + (size_t)(n0 + n) * 256 + c4;
        vf4 a = __builtin_nontemporal_load(ms);
        #pragma unroll
        for (int d = 1; d < 16; ++d)
            a += __builtin_nontemporal_load(ms + d * 16);
        *reinterpret_cast<vf4*>(&ldsA[n * X1S + c4 * 4])      = f;
        *reinterpret_cast<vf4*>(&ldsA[n * X1S + 64 + c4 * 4]) = h;
        *reinterpret_cast<vf4*>(&ldsB[n * X2S + c4 * 4])      = a;
    }
    __syncthreads();

    const int node = t & 63;
    const int sub  = __builtin_amdgcn_readfirstlane(t >> 6);  // wave id 0..7, SGPR-uniform

    // ---------- Phase 2: h1 = relu(x1 @ w1a + b1a), j-slice of 12 ----------
    float acc1[12];
    {
        const float* b = b1a + sub * 12;
        #pragma unroll
        for (int j = 0; j < 12; ++j) acc1[j] = b[j];
        const float4* xr = reinterpret_cast<const float4*>(&ldsA[node * X1S]);
        #pragma unroll 4
        for (int k4 = 0; k4 < 32; ++k4) {
            float4 x = xr[k4];
            const float* w0 = w1a + (k4 * 4) * 96 + sub * 12;
            #pragma unroll
            for (int j = 0; j < 12; ++j) acc1[j] = fmaf(x.x, w0[j],       acc1[j]);
            #pragma unroll
            for (int j = 0; j < 12; ++j) acc1[j] = fmaf(x.y, w0[96 + j],  acc1[j]);
            #pragma unroll
            for (int j = 0; j < 12; ++j) acc1[j] = fmaf(x.z, w0[192 + j], acc1[j]);
            #pragma unroll
            for (int j = 0; j < 12; ++j) acc1[j] = fmaf(x.w, w0[288 + j], acc1[j]);
        }
    }
    __syncthreads();                     // all x1 reads done; reuse ldsA for h1
    {
        float4* hrow = reinterpret_cast<float4*>(&ldsA[node * H1S + sub * 12]);
        #pragma unroll
        for (int j4 = 0; j4 < 3; ++j4) {
            float4 v;
            v.x = fmaxf(acc1[j4*4+0], 0.f);
            v.y = fmaxf(acc1[j4*4+1], 0.f);
            v.z = fmaxf(acc1[j4*4+2], 0.f);
            v.w = fmaxf(acc1[j4*4+3], 0.f);
            hrow[j4] = v;
        }
    }
    __syncthreads();

    // ---------- Phase 3: r1 = tanh(h1 @ w1b + b1b), j-slice of 8 ----------
    float r1v[8];
    {
        float acc[8];
        const float* b = b1b + sub * 8;
        #pragma unroll
        for (int j = 0; j < 8; ++j) acc[j] = b[j];
        const float4* hr = reinterpret_cast<const float4*>(&ldsA[node * H1S]);
        #pragma unroll 4
        for (int k4 = 0; k4 < 24; ++k4) {
            float4 x = hr[k4];
            const float* w0 = w1b + (k4 * 4) * 64 + sub * 8;
            #pragma unroll
            for (int j = 0; j < 8; ++j) acc[j] = fmaf(x.x, w0[j],       acc[j]);
            #pragma unroll
            for (int j = 0; j < 8; ++j) acc[j] = fmaf(x.y, w0[64 + j],  acc[j]);
            #pragma unroll
            for (int j = 0; j < 8; ++j) acc[j] = fmaf(x.z, w0[128 + j], acc[j]);
            #pragma unroll
            for (int j = 0; j < 8; ++j) acc[j] = fmaf(x.w, w0[192 + j], acc[j]);
        }
        #pragma unroll
        for (int j = 0; j < 8; ++j) r1v[j] = fast_tanh(acc[j]);
    }

    // ---------- Phase 4: h2 = relu(x2 @ w2a + b2a), j-slice of 8 ----------
    float h2v[8];
    {
        float acc[8];
        const float* b = b2a + sub * 8;
        #pragma unroll
        for (int j = 0; j < 8; ++j) acc[j] = b[j];
        const float4* xr = reinterpret_cast<const float4*>(&ldsB[node * X2S]);
        #pragma unroll 4
        for (int k4 = 0; k4 < 16; ++k4) {
            float4 x = xr[k4];
            const float* w0 = w2a + (k4 * 4) * 64 + sub * 8;
            #pragma unroll
            for (int j = 0; j < 8; ++j) acc[j] = fmaf(x.x, w0[j],       acc[j]);
            #pragma unroll
            for (int j = 0; j < 8; ++j) acc[j] = fmaf(x.y, w0[64 + j],  acc[j]);
            #pragma unroll
            for (int j = 0; j < 8; ++j) acc[j] = fmaf(x.z, w0[128 + j], acc[j]);
            #pragma unroll
            for (int j = 0; j < 8; ++j) acc[j] = fmaf(x.w, w0[192 + j], acc[j]);
        }
        #pragma unroll
        for (int j = 0; j < 8; ++j) h2v[j] = fmaxf(acc[j], 0.f);
    }
    __syncthreads();                     // all x2 reads done; reuse ldsB for h2
    {
        float4* hrow = reinterpret_cast<float4*>(&ldsB[node * X2S + sub * 8]);
        hrow[0] = make_float4(h2v[0], h2v[1], h2v[2], h2v[3]);
        hrow[1] = make_float4(h2v[4], h2v[5], h2v[6], h2v[7]);
    }
    __syncthreads();

    // ---------- Phase 5: r2 = tanh(h2 @ w2b + b2b), j-slice of 8 ----------
    float r2v[8];
    {
        float acc[8];
        const float* b = b2b + sub * 8;
        #pragma unroll
        for (int j = 0; j < 8; ++j) acc[j] = b[j];
        const float4* hr = reinterpret_cast<const float4*>(&ldsB[node * X2S]);
        #pragma unroll 4
        for (int k4 = 0; k4 < 16; ++k4) {
            float4 x = hr[k4];
            const float* w0 = w2b + (k4 * 4) * 64 + sub * 8;
            #pragma unroll
            for (int j = 0; j < 8; ++j) acc[j] = fmaf(x.x, w0[j],       acc[j]);
            #pragma unroll
            for (int j = 0; j < 8; ++j) acc[j] = fmaf(x.y, w0[64 + j],  acc[j]);
            #pragma unroll
            for (int j = 0; j < 8; ++j) acc[j] = fmaf(x.z, w0[128 + j], acc[j]);
            #pragma unroll
            for (int j = 0; j < 8; ++j) acc[j] = fmaf(x.w, w0[192 + j], acc[j]);
        }
        #pragma unroll
        for (int j = 0; j < 8; ++j) r2v[j] = fast_tanh(acc[j]);
    }

    // ---------- Phase 6: row L2 norm + write ----------
    float s = 0.f;
    #pragma unroll
    for (int j = 0; j < 8; ++j) s = fmaf(r1v[j], r1v[j], s);
    #pragma unroll
    for (int j = 0; j < 8; ++j) s = fmaf(r2v[j], r2v[j], s);
    ldsS[node * 8 + sub] = s;
    __syncthreads();
    const float4* sp = reinterpret_cast<const float4*>(&ldsS[node * 8]);
    float4 s0 = sp[0], s1 = sp[1];
    float rn = rsqrtf(s0.x + s0.y + s0.z + s0.w + s1.x + s1.y + s1.z + s1.w);

    float* orow = out + (size_t)(n0 + node) * 128 + sub * 8;
    vf4 o0 = {r1v[0]*rn, r1v[1]*rn, r1v[2]*rn, r1v[3]*rn};
    vf4 o1 = {r1v[4]*rn, r1v[5]*rn, r1v[6]*rn, r1v[7]*rn};
    vf4 o2 = {r2v[0]*rn, r2v[1]*rn, r2v[2]*rn, r2v[3]*rn};
    vf4 o3 = {r2v[4]*rn, r2v[5]*rn, r2v[6]*rn, r2v[7]*rn};
    __builtin_nontemporal_store(o0, reinterpret_cast<vf4*>(orow));
    __builtin_nontemporal_store(o1, reinterpret_cast<vf4*>(orow) + 1);
    __builtin_nontemporal_store(o2, reinterpret_cast<vf4*>(orow + 64));
    __builtin_nontemporal_store(o3, reinterpret_cast<vf4*>(orow + 64) + 1);
}

extern "C" void kernel_launch(void* const* d_in, const int* in_sizes, int n_in,
                              void* d_out, int out_size, void* d_ws, size_t ws_size,
                              hipStream_t stream) {
    const float* feat = (const float*)d_in[0];
    const float* hid  = (const float*)d_in[1];
    const float* mail = (const float*)d_in[2];
    const float* w1a  = (const float*)d_in[3];
    const float* b1a  = (const float*)d_in[4];
    const float* w1b  = (const float*)d_in[5];
    const float* b1b  = (const float*)d_in[6];
    const float* w2a  = (const float*)d_in[7];
    const float* b2a  = (const float*)d_in[8];
    const float* w2b  = (const float*)d_in[9];
    const float* b2b  = (const float*)d_in[10];
    float* out = (float*)d_out;

    const int N = in_sizes[0] / 64;          // 200000
    const int blocks = N / NB;               // 3125

    node_net_kernel<<<blocks, THREADS, 0, stream>>>(
        feat, hid, mail, w1a, b1a, w1b, b1b, w2a, b2a, w2b, b2b, out);
}